// Round 1
// 5891.175 us; speedup vs baseline: 1.3521x; 1.3521x over previous
//
#include <hip/hip_runtime.h>
#include <math.h>

namespace {
constexpr int WSZ   = 7;
constexpr int HW    = 49;
constexpr int CIN   = 192;
constexpr int HEADS = 6;
constexpr int CH    = 32;   // CIN / HEADS
constexpr int IMG   = 224;

// One block per 7x7 window. 256 threads = 4 waves; lane = pixel (49/64 active).
// v8: stage x ONCE (reused by all 6 heads), wave-local phases A/B/C (no barriers),
// q-column in registers for phase D, 4-thread-per-column softmax, 25 barriers/block
// (was 96), no per-head staging loop.
__global__ __launch_bounds__(256, 2)
void win_attn_fused(const float* __restrict__ x,
                    const float* __restrict__ w_qkv,
                    const float* __restrict__ b_qkv,
                    const float* __restrict__ w_dw,
                    const float* __restrict__ b_dw,
                    const float* __restrict__ w_proj,
                    const float* __restrict__ b_proj,
                    const float* __restrict__ temperature,
                    float* __restrict__ out)
{
    __shared__ float xs[CIN][HW + 1];   // 38400 B: whole input window, staged once
    __shared__ float qh[96][HW];        // 18816 B: this head's q(0-31)/k(32-63)/v(64-95)
    __shared__ float attnb[HW][HW];     //  9604 B: attn[n][m]
    __shared__ float outb[CH][HW];      //  6272 B: head attention output
    // total 73092 B -> 2 blocks/CU

    const int tid  = threadIdx.x;
    const int lane = tid & 63;
    const int wv   = __builtin_amdgcn_readfirstlane(tid >> 6);  // wave id, uniform

    const int wi   = blockIdx.x;          // [0,4096)
    const int b    = wi >> 10;
    const int hy   = (wi >> 5) & 31;
    const int wx   = wi & 31;
    const int row0 = hy * WSZ, col0 = wx * WSZ;

    const int  p   = lane;                // pixel within window
    const bool act = (lane < HW);
    const int  py  = p / WSZ, px = p % WSZ;

    // ---- stage the whole 192x49 window ONCE ----
    for (int i = tid; i < CIN * HW; i += 256) {
        int c = i / HW, pp = i - c * HW;
        int gy = row0 + pp / WSZ, gx = col0 + pp % WSZ;
        xs[c][pp] = x[((b * CIN + c) * IMG + gy) * IMG + gx];
    }
    __syncthreads();

    float pacc[48];                       // proj accumulator: oc = 48*wv + j
    #pragma unroll
    for (int j = 0; j < 48; ++j) pacc[j] = 0.f;

    for (int h = 0; h < HEADS; ++h) {
        // row -> qkv output-channel map for this wave (uniform)
        int oj[24];
        #pragma unroll
        for (int j = 0; j < 24; ++j) {
            int r = 24 * wv + j;          // [0,96): 0-31 q, 32-63 k, 64-95 v
            oj[j] = (r < 32) ? (CH * h + r)
                  : (r < 64) ? (CIN + CH * h + (r - 32))
                             : (2 * CIN + CH * h + (r - 64));
        }

        // --- Phase A (wave-local, NO barrier): qkv_raw = W_qkv[oj] @ x_window ---
        if (act) {
            float acc[24];
            #pragma unroll
            for (int j = 0; j < 24; ++j) acc[j] = 0.f;
            #pragma unroll 4
            for (int c = 0; c < CIN; ++c) {
                float xv = xs[c][p];                 // 1 ds_read feeds 24 fma
                #pragma unroll
                for (int j = 0; j < 24; ++j)
                    acc[j] = fmaf(w_qkv[oj[j] * CIN + c], xv, acc[j]);
            }
            #pragma unroll
            for (int j = 0; j < 24; ++j)
                qh[24 * wv + j][p] = acc[j] + b_qkv[oj[j]];
        }

        // --- Phase B (wave-local, NO barrier): depthwise 3x3, zero-padded in-window.
        // Reads/writes only this wave's own rows; in-wave LDS RAW ordering is
        // guaranteed by compiler-inserted lgkmcnt waits (lockstep lanes). ---
        if (act) {
            float cv[24];
            #pragma unroll
            for (int j = 0; j < 24; ++j) {
                int r = 24 * wv + j, o = oj[j];
                float s = b_dw[o];
                #pragma unroll
                for (int ky = 0; ky < 3; ++ky) {
                    int yy = py + ky - 1;
                    #pragma unroll
                    for (int kx = 0; kx < 3; ++kx) {
                        int xx = px + kx - 1;
                        bool ok = (yy >= 0) & (yy < WSZ) & (xx >= 0) & (xx < WSZ);
                        float v = ok ? qh[r][yy * WSZ + xx] : 0.f;
                        s = fmaf(w_dw[o * 9 + ky * 3 + kx], v, s);
                    }
                }
                cv[j] = s;
            }
            #pragma unroll
            for (int j = 0; j < 24; ++j) qh[24 * wv + j][p] = cv[j];
        }
        __syncthreads();   // (1) all waves' qkv_dw rows visible

        // --- Phase C (wave-local, redundant per wave): 1/max(||q||,eps), 1/max(||k||,eps)
        float rnq = 0.f, rnk = 0.f;
        if (act) {
            float sq = 0.f, sk = 0.f;
            #pragma unroll
            for (int cc = 0; cc < CH; ++cc) {
                float a  = qh[cc][p];      sq = fmaf(a, a, sq);
                float bb = qh[CH + cc][p]; sk = fmaf(bb, bb, sk);
            }
            rnq = 1.0f / fmaxf(sqrtf(sq), 1e-12f);
            rnk = 1.0f / fmaxf(sqrtf(sk), 1e-12f);
        }

        // own q column into registers (halves phase-D LDS reads)
        float qreg[CH];
        if (act) {
            #pragma unroll
            for (int cc = 0; cc < CH; ++cc) qreg[cc] = qh[cc][p];
        }

        // --- Phase D: attn[n][m] = t * rk[n] * rq[m] * sum_c k[c][n] q[c][m] ---
        const float tmp = temperature[h];
        {
            int n0 = wv * 13;
            int n1 = (n0 + 13 < HW) ? (n0 + 13) : HW;
            for (int n = n0; n < n1; ++n) {
                float rkn = __shfl(rnk, n);          // k-norm lives in lane n
                if (act) {
                    float s = 0.f;
                    #pragma unroll
                    for (int cc = 0; cc < CH; ++cc)
                        s = fmaf(qh[CH + cc][n], qreg[cc], s);   // broadcast * reg
                    attnb[n][p] = s * tmp * rkn * rnq;
                }
            }
        }
        __syncthreads();   // (2)

        // --- Phase E: softmax over n per column m; 4 threads cooperate per column ---
        {
            int m = tid >> 2, sub = tid & 3;
            if (m < HW) {
                int na = sub * 13;
                int nb = (na + 13 < HW) ? (na + 13) : HW;
                float mx = -1e30f;
                for (int n = na; n < nb; ++n) mx = fmaxf(mx, attnb[n][m]);
                mx = fmaxf(mx, __shfl_xor(mx, 1));
                mx = fmaxf(mx, __shfl_xor(mx, 2));
                float sum = 0.f;
                for (int n = na; n < nb; ++n) {
                    float e = __expf(attnb[n][m] - mx);
                    attnb[n][m] = e;
                    sum += e;
                }
                sum += __shfl_xor(sum, 1);
                sum += __shfl_xor(sum, 2);
                float inv = 1.0f / sum;
                for (int n = na; n < nb; ++n) attnb[n][m] *= inv;
            }
        }
        __syncthreads();   // (3)

        // --- Phase F: out[cc][m] = sum_n v[cc][n] * attn[n][m] ---
        if (act) {
            float s[8];
            #pragma unroll
            for (int j = 0; j < 8; ++j) s[j] = 0.f;
            for (int n = 0; n < HW; ++n) {
                float a = attnb[n][p];               // 1 lane read feeds 8 fma
                #pragma unroll
                for (int j = 0; j < 8; ++j)
                    s[j] = fmaf(qh[2 * CH + 8 * wv + j][n], a, s[j]);
            }
            #pragma unroll
            for (int j = 0; j < 8; ++j) outb[8 * wv + j][p] = s[j];
        }
        __syncthreads();   // (4)

        // --- Phase G: proj partial: pacc[oc] += W_proj[oc, 32h+cc] * out[cc] ---
        // No trailing barrier: next head's first LDS writes (qh in phase A) are
        // separated from this head's qh/attnb readers by barriers (1)-(4), and
        // outb is rewritten only after next head's barrier (3).
        if (act) {
            #pragma unroll 4
            for (int cc = 0; cc < CH; ++cc) {
                float ov = outb[cc][p];              // 1 ds_read feeds 48 fma
                #pragma unroll
                for (int j = 0; j < 48; ++j)
                    pacc[j] = fmaf(w_proj[(48 * wv + j) * CIN + CH * h + cc], ov, pacc[j]);
            }
        }
    }

    // --- epilogue: bias + window-reverse store ---
    if (act) {
        #pragma unroll
        for (int j = 0; j < 48; ++j) {
            int oc = 48 * wv + j;
            out[((b * CIN + oc) * IMG + row0 + py) * IMG + col0 + px] = pacc[j] + b_proj[oc];
        }
    }
}
} // namespace

extern "C" void kernel_launch(void* const* d_in, const int* in_sizes, int n_in,
                              void* d_out, int out_size, void* d_ws, size_t ws_size,
                              hipStream_t stream) {
    const float* x      = (const float*)d_in[0];
    const float* w_qkv  = (const float*)d_in[1];
    const float* b_qkv  = (const float*)d_in[2];
    const float* w_dw   = (const float*)d_in[3];
    const float* b_dw   = (const float*)d_in[4];
    const float* w_proj = (const float*)d_in[5];
    const float* b_proj = (const float*)d_in[6];
    const float* temp   = (const float*)d_in[7];

    win_attn_fused<<<dim3(4096), dim3(256), 0, stream>>>(
        x, w_qkv, b_qkv, w_dw, b_dw, w_proj, b_proj, temp, (float*)d_out);
}

// Round 2
// 4514.907 us; speedup vs baseline: 1.7642x; 1.3048x over previous
//
#include <hip/hip_runtime.h>
#include <math.h>

namespace {
constexpr int WSZ   = 7;
constexpr int HW    = 49;
constexpr int CIN   = 192;
constexpr int HEADS = 6;
constexpr int CH    = 32;   // CIN / HEADS
constexpr int IMG   = 224;
constexpr int ASTR  = 54;   // attnb row stride: 6*54 % 32 == 4 -> softmax sub-groups spread banks

// One block per 7x7 window, 512 threads = 8 waves; lane = pixel (49/64 active).
// v9: 8-wave blocks halve per-wave work -> 16 waves/CU (4/SIMD) at 2 blocks/CU,
// doubling latency hiding. attnb stride 54 kills the softmax bank conflicts.
__global__ __launch_bounds__(512, 4)
void win_attn_fused(const float* __restrict__ x,
                    const float* __restrict__ w_qkv,
                    const float* __restrict__ b_qkv,
                    const float* __restrict__ w_dw,
                    const float* __restrict__ b_dw,
                    const float* __restrict__ w_proj,
                    const float* __restrict__ b_proj,
                    const float* __restrict__ temperature,
                    float* __restrict__ out)
{
    __shared__ float xs[CIN][HW];       // 37632 B: whole input window, staged once
    __shared__ float qh[96][HW];        // 18816 B: this head's q(0-31)/k(32-63)/v(64-95)
    __shared__ float attnb[HW][ASTR];   // 10584 B: attn[n][m], stride 54
    __shared__ float outb[CH][HW];      //  6272 B: head attention output
    // total 73304 B -> 2 blocks/CU -> 16 waves/CU = 4 waves/SIMD

    const int tid  = threadIdx.x;
    const int lane = tid & 63;
    const int wv   = __builtin_amdgcn_readfirstlane(tid >> 6);  // wave id 0..7, uniform

    const int wi   = blockIdx.x;          // [0,4096)
    const int b    = wi >> 10;
    const int hy   = (wi >> 5) & 31;
    const int wx   = wi & 31;
    const int row0 = hy * WSZ, col0 = wx * WSZ;

    const int  p   = lane;                // pixel within window
    const bool act = (lane < HW);
    const int  py  = p / WSZ, px = p % WSZ;

    // ---- stage the whole 192x49 window ONCE ----
    for (int i = tid; i < CIN * HW; i += 512) {
        int c = i / HW, pp = i - c * HW;
        int gy = row0 + pp / WSZ, gx = col0 + pp % WSZ;
        xs[c][pp] = x[((b * CIN + c) * IMG + gy) * IMG + gx];
    }
    __syncthreads();

    float pacc[24];                       // proj accumulator: oc = 24*wv + j
    #pragma unroll
    for (int j = 0; j < 24; ++j) pacc[j] = 0.f;

    for (int h = 0; h < HEADS; ++h) {
        // row -> qkv output-channel map for this wave (12 rows/wave, uniform)
        int oj[12];
        #pragma unroll
        for (int j = 0; j < 12; ++j) {
            int r = 12 * wv + j;          // [0,96): 0-31 q, 32-63 k, 64-95 v
            oj[j] = (r < 32) ? (CH * h + r)
                  : (r < 64) ? (CIN + CH * h + (r - 32))
                             : (2 * CIN + CH * h + (r - 64));
        }

        // --- Phase A (wave-local, NO barrier): qkv_raw = W_qkv[oj] @ x_window ---
        if (act) {
            float acc[12];
            #pragma unroll
            for (int j = 0; j < 12; ++j) acc[j] = 0.f;
            #pragma unroll 4
            for (int c = 0; c < CIN; ++c) {
                float xv = xs[c][p];                 // 1 ds_read feeds 12 fma
                #pragma unroll
                for (int j = 0; j < 12; ++j)
                    acc[j] = fmaf(w_qkv[oj[j] * CIN + c], xv, acc[j]);
            }
            #pragma unroll
            for (int j = 0; j < 12; ++j)
                qh[12 * wv + j][p] = acc[j] + b_qkv[oj[j]];
        }

        // --- Phase B (wave-local, NO barrier): depthwise 3x3, zero-padded in-window.
        // Reads/writes only this wave's own rows; in-wave LDS RAW ordering is
        // guaranteed by compiler-inserted lgkmcnt waits (lockstep lanes). ---
        if (act) {
            float cv[12];
            #pragma unroll
            for (int j = 0; j < 12; ++j) {
                int r = 12 * wv + j, o = oj[j];
                float s = b_dw[o];
                #pragma unroll
                for (int ky = 0; ky < 3; ++ky) {
                    int yy = py + ky - 1;
                    #pragma unroll
                    for (int kx = 0; kx < 3; ++kx) {
                        int xx = px + kx - 1;
                        bool ok = (yy >= 0) & (yy < WSZ) & (xx >= 0) & (xx < WSZ);
                        float v = ok ? qh[r][yy * WSZ + xx] : 0.f;
                        s = fmaf(w_dw[o * 9 + ky * 3 + kx], v, s);
                    }
                }
                cv[j] = s;
            }
            #pragma unroll
            for (int j = 0; j < 12; ++j) qh[12 * wv + j][p] = cv[j];
        }
        __syncthreads();   // (1) all waves' qkv_dw rows visible

        // --- Phase C (wave-local, redundant per wave): 1/max(||q||,eps), 1/max(||k||,eps)
        float rnq = 0.f, rnk = 0.f;
        if (act) {
            float sq = 0.f, sk = 0.f;
            #pragma unroll
            for (int cc = 0; cc < CH; ++cc) {
                float a  = qh[cc][p];      sq = fmaf(a, a, sq);
                float bb = qh[CH + cc][p]; sk = fmaf(bb, bb, sk);
            }
            rnq = 1.0f / fmaxf(sqrtf(sq), 1e-12f);
            rnk = 1.0f / fmaxf(sqrtf(sk), 1e-12f);
        }

        // own q column into registers
        float qreg[CH];
        if (act) {
            #pragma unroll
            for (int cc = 0; cc < CH; ++cc) qreg[cc] = qh[cc][p];
        }

        // --- Phase D: attn[n][m] = t * rk[n] * rq[m] * sum_c k[c][n] q[c][m] ---
        const float tmp = temperature[h];
        {
            int n0 = (wv * HW) >> 3;
            int n1 = ((wv + 1) * HW) >> 3;
            for (int n = n0; n < n1; ++n) {
                float rkn = __shfl(rnk, n);          // k-norm lives in lane n
                if (act) {
                    float s = 0.f;
                    #pragma unroll
                    for (int cc = 0; cc < CH; ++cc)
                        s = fmaf(qh[CH + cc][n], qreg[cc], s);   // broadcast * reg
                    attnb[n][p] = s * tmp * rkn * rnq;
                }
            }
        }
        __syncthreads();   // (2)

        // --- Phase E: softmax over n per column m; 8 threads cooperate per column ---
        {
            int m = tid >> 3, sub = tid & 7;
            if (m < HW) {
                int na = (sub * HW) >> 3;
                int nb = ((sub + 1) * HW) >> 3;
                float mx = -1e30f;
                for (int n = na; n < nb; ++n) mx = fmaxf(mx, attnb[n][m]);
                mx = fmaxf(mx, __shfl_xor(mx, 1));
                mx = fmaxf(mx, __shfl_xor(mx, 2));
                mx = fmaxf(mx, __shfl_xor(mx, 4));
                float sum = 0.f;
                for (int n = na; n < nb; ++n) {
                    float e = __expf(attnb[n][m] - mx);
                    attnb[n][m] = e;
                    sum += e;
                }
                sum += __shfl_xor(sum, 1);
                sum += __shfl_xor(sum, 2);
                sum += __shfl_xor(sum, 4);
                float inv = 1.0f / sum;
                for (int n = na; n < nb; ++n) attnb[n][m] *= inv;
            }
        }
        __syncthreads();   // (3)

        // --- Phase F: out[cc][m] = sum_n v[cc][n] * attn[n][m]; 4 channels/wave ---
        if (act) {
            float s[4];
            #pragma unroll
            for (int j = 0; j < 4; ++j) s[j] = 0.f;
            for (int n = 0; n < HW; ++n) {
                float a = attnb[n][p];               // 1 lane read feeds 4 fma
                #pragma unroll
                for (int j = 0; j < 4; ++j)
                    s[j] = fmaf(qh[2 * CH + 4 * wv + j][n], a, s[j]);
            }
            #pragma unroll
            for (int j = 0; j < 4; ++j) outb[4 * wv + j][p] = s[j];
        }
        __syncthreads();   // (4)

        // --- Phase G: proj partial: pacc[oc] += W_proj[oc, 32h+cc] * out[cc] ---
        // No trailing barrier: next head's qh writes (phase A) only conflict with
        // this head's F readers, which all passed barrier (4); attnb is rewritten
        // only after next head's barrier (1)->(2) path; outb after next (3).
        if (act) {
            #pragma unroll 4
            for (int cc = 0; cc < CH; ++cc) {
                float ov = outb[cc][p];              // 1 ds_read feeds 24 fma
                #pragma unroll
                for (int j = 0; j < 24; ++j)
                    pacc[j] = fmaf(w_proj[(24 * wv + j) * CIN + CH * h + cc], ov, pacc[j]);
            }
        }
    }

    // --- epilogue: bias + window-reverse store ---
    if (act) {
        #pragma unroll
        for (int j = 0; j < 24; ++j) {
            int oc = 24 * wv + j;
            out[((b * CIN + oc) * IMG + row0 + py) * IMG + col0 + px] = pacc[j] + b_proj[oc];
        }
    }
}
} // namespace

extern "C" void kernel_launch(void* const* d_in, const int* in_sizes, int n_in,
                              void* d_out, int out_size, void* d_ws, size_t ws_size,
                              hipStream_t stream) {
    const float* x      = (const float*)d_in[0];
    const float* w_qkv  = (const float*)d_in[1];
    const float* b_qkv  = (const float*)d_in[2];
    const float* w_dw   = (const float*)d_in[3];
    const float* b_dw   = (const float*)d_in[4];
    const float* w_proj = (const float*)d_in[5];
    const float* b_proj = (const float*)d_in[6];
    const float* temp   = (const float*)d_in[7];

    win_attn_fused<<<dim3(4096), dim3(512), 0, stream>>>(
        x, w_qkv, b_qkv, w_dw, b_dw, w_proj, b_proj, temp, (float*)d_out);
}

// Round 4
// 3888.430 us; speedup vs baseline: 2.0485x; 1.1611x over previous
//
#include <hip/hip_runtime.h>
#include <math.h>

namespace {
constexpr int WSZ   = 7;
constexpr int HW    = 49;
constexpr int CIN   = 192;
constexpr int HEADS = 6;
constexpr int CH    = 32;   // CIN / HEADS
constexpr int IMG   = 224;
constexpr int ASTR  = 54;   // attnb row stride (R2: zero conflicts)
constexpr int XSTR  = 196;  // xs row stride: 196 % 32 == 4 -> conflict-free b128 reads
constexpr int NWX   = 32;   // windows per image row
constexpr int CHUNK = CIN * HW;          // 9408 floats per window chunk
constexpr int NWIN  = 4 * 32 * 32;       // 4096 windows

// ---------- pre: (B,C,H,W) -> window-major [win][c][p], all accesses coalesced ----------
__global__ void win_pre(const float* __restrict__ x, float* __restrict__ win)
{
    __shared__ float tile[8][WSZ][IMG];           // 50176 B
    const int blk = blockIdx.x;
    const int cg  = blk % 24;
    const int hy  = (blk / 24) % 32;
    const int b   = blk / (24 * 32);
    const int c0  = cg * 8, row0 = hy * WSZ;

    for (int i = threadIdx.x; i < 8 * WSZ * IMG; i += 256) {
        int gx = i % IMG, ry = (i / IMG) % WSZ, c = i / (IMG * WSZ);
        tile[c][ry][gx] = x[(((size_t)(b * CIN + c0 + c)) * IMG + row0 + ry) * IMG + gx];
    }
    __syncthreads();
    for (int i = threadIdx.x; i < NWX * 8 * HW; i += 256) {
        int p = i % HW, c = (i / HW) % 8, wx = i / (HW * 8);
        size_t wi = ((size_t)(b * 32 + hy)) * NWX + wx;
        win[wi * CHUNK + (c0 + c) * HW + p] = tile[c][p / WSZ][wx * WSZ + p % WSZ];
    }
}

// ---------- post: window-major [win][c][p] -> (B,C,H,W), all accesses coalesced ----------
__global__ void win_post(const float* __restrict__ win, float* __restrict__ out)
{
    __shared__ float tile[8][WSZ][IMG];
    const int blk = blockIdx.x;
    const int cg  = blk % 24;
    const int hy  = (blk / 24) % 32;
    const int b   = blk / (24 * 32);
    const int c0  = cg * 8, row0 = hy * WSZ;

    for (int i = threadIdx.x; i < NWX * 8 * HW; i += 256) {
        int p = i % HW, c = (i / HW) % 8, wx = i / (HW * 8);
        size_t wi = ((size_t)(b * 32 + hy)) * NWX + wx;
        tile[c][p / WSZ][wx * WSZ + p % WSZ] = win[wi * CHUNK + (c0 + c) * HW + p];
    }
    __syncthreads();
    for (int i = threadIdx.x; i < 8 * WSZ * IMG; i += 256) {
        int gx = i % IMG, ry = (i / IMG) % WSZ, c = i / (IMG * WSZ);
        out[(((size_t)(b * CIN + c0 + c)) * IMG + row0 + ry) * IMG + gx] = tile[c][ry][gx];
    }
}

// ---------- main (fast path): one block per window, dense chunk I/O, in-place ----------
__global__ __launch_bounds__(512, 4)
void win_attn_fused(float* __restrict__ win,
                    const float* __restrict__ w_qkv,
                    const float* __restrict__ b_qkv,
                    const float* __restrict__ w_dw,
                    const float* __restrict__ b_dw,
                    const float* __restrict__ w_proj,
                    const float* __restrict__ b_proj,
                    const float* __restrict__ temperature)
{
    __shared__ __align__(16) float xs[HW][XSTR];  // 38416 B: window, [pixel][channel]
    __shared__ float qh[96][HW];                  // 18816 B: q(0-31)/k(32-63)/v(64-95)
    __shared__ float attnb[HW][ASTR];             // 10584 B
    __shared__ float outb[CH][HW];                //  6272 B
    // total ~74 KB -> 2 blocks/CU -> 16 waves/CU

    const int tid  = threadIdx.x;
    const int lane = tid & 63;
    const int wv   = __builtin_amdgcn_readfirstlane(tid >> 6);

    const int wi   = blockIdx.x;          // [0,4096)
    const int  p   = lane;
    const bool act = (lane < HW);
    const int  py  = p / WSZ, px = p % WSZ;

    // ---- stage window chunk (dense, coalesced) with [c][p] -> [p][c] transpose ----
    const float* __restrict__ xchunk = win + (size_t)wi * CHUNK;
    for (int i = tid; i < CHUNK; i += 512) {
        int c = i / HW, pp = i - c * HW;
        xs[pp][c] = xchunk[i];
    }
    __syncthreads();

    float pacc[24];
    #pragma unroll
    for (int j = 0; j < 24; ++j) pacc[j] = 0.f;

    for (int h = 0; h < HEADS; ++h) {
        int oj[12];
        #pragma unroll
        for (int j = 0; j < 12; ++j) {
            int r = 12 * wv + j;          // [0,96): 0-31 q, 32-63 k, 64-95 v
            oj[j] = (r < 32) ? (CH * h + r)
                  : (r < 64) ? (CIN + CH * h + (r - 32))
                             : (2 * CIN + CH * h + (r - 64));
        }

        // --- Phase A (wave-local, NO barrier): float4 x * uniform (scalar) weights ---
        if (act) {
            float acc[12];
            #pragma unroll
            for (int j = 0; j < 12; ++j) acc[j] = 0.f;
            const float4* xrow = (const float4*)(&xs[p][0]);
            #pragma unroll 2
            for (int c4 = 0; c4 < CIN / 4; ++c4) {
                float4 xv = xrow[c4];
                #pragma unroll
                for (int j = 0; j < 12; ++j) {
                    const float* wr = &w_qkv[oj[j] * CIN + 4 * c4];
                    float a = acc[j];
                    a = fmaf(wr[0], xv.x, a);
                    a = fmaf(wr[1], xv.y, a);
                    a = fmaf(wr[2], xv.z, a);
                    a = fmaf(wr[3], xv.w, a);
                    acc[j] = a;
                }
            }
            #pragma unroll
            for (int j = 0; j < 12; ++j)
                qh[12 * wv + j][p] = acc[j] + b_qkv[oj[j]];
        }

        // --- Phase B (wave-local, NO barrier): depthwise 3x3 within window ---
        if (act) {
            float cv[12];
            #pragma unroll
            for (int j = 0; j < 12; ++j) {
                int r = 12 * wv + j, o = oj[j];
                float s = b_dw[o];
                #pragma unroll
                for (int ky = 0; ky < 3; ++ky) {
                    int yy = py + ky - 1;
                    #pragma unroll
                    for (int kx = 0; kx < 3; ++kx) {
                        int xx = px + kx - 1;
                        bool ok = (yy >= 0) & (yy < WSZ) & (xx >= 0) & (xx < WSZ);
                        float v = ok ? qh[r][yy * WSZ + xx] : 0.f;
                        s = fmaf(w_dw[o * 9 + ky * 3 + kx], v, s);
                    }
                }
                cv[j] = s;
            }
            #pragma unroll
            for (int j = 0; j < 12; ++j) qh[12 * wv + j][p] = cv[j];
        }
        __syncthreads();   // (1)

        // --- Phase C: per-pixel reciprocal norms (wave-local, redundant) ---
        float rnq = 0.f, rnk = 0.f;
        if (act) {
            float sq = 0.f, sk = 0.f;
            #pragma unroll
            for (int cc = 0; cc < CH; ++cc) {
                float a  = qh[cc][p];      sq = fmaf(a, a, sq);
                float bb = qh[CH + cc][p]; sk = fmaf(bb, bb, sk);
            }
            rnq = 1.0f / fmaxf(sqrtf(sq), 1e-12f);
            rnk = 1.0f / fmaxf(sqrtf(sk), 1e-12f);
        }

        float qreg[CH];
        if (act) {
            #pragma unroll
            for (int cc = 0; cc < CH; ++cc) qreg[cc] = qh[cc][p];
        }

        // --- Phase D: attn[n][m] = t * rk[n] * rq[m] * sum_c k[c][n] q[c][m] ---
        const float tmp = temperature[h];
        {
            int n0 = (wv * HW) >> 3;
            int n1 = ((wv + 1) * HW) >> 3;
            for (int n = n0; n < n1; ++n) {
                float rkn = __shfl(rnk, n);
                if (act) {
                    float s = 0.f;
                    #pragma unroll
                    for (int cc = 0; cc < CH; ++cc)
                        s = fmaf(qh[CH + cc][n], qreg[cc], s);
                    attnb[n][p] = s * tmp * rkn * rnq;
                }
            }
        }
        __syncthreads();   // (2)

        // --- Phase E: softmax over n per column m; 8 threads per column ---
        {
            int m = tid >> 3, sub = tid & 7;
            if (m < HW) {
                int na = (sub * HW) >> 3;
                int nb = ((sub + 1) * HW) >> 3;
                float mx = -1e30f;
                for (int n = na; n < nb; ++n) mx = fmaxf(mx, attnb[n][m]);
                mx = fmaxf(mx, __shfl_xor(mx, 1));
                mx = fmaxf(mx, __shfl_xor(mx, 2));
                mx = fmaxf(mx, __shfl_xor(mx, 4));
                float sum = 0.f;
                for (int n = na; n < nb; ++n) {
                    float e = __expf(attnb[n][m] - mx);
                    attnb[n][m] = e;
                    sum += e;
                }
                sum += __shfl_xor(sum, 1);
                sum += __shfl_xor(sum, 2);
                sum += __shfl_xor(sum, 4);
                float inv = 1.0f / sum;
                for (int n = na; n < nb; ++n) attnb[n][m] *= inv;
            }
        }
        __syncthreads();   // (3)

        // --- Phase F: out[cc][m] = sum_n v[cc][n] * attn[n][m]; 4 ch/wave ---
        if (act) {
            float s[4];
            #pragma unroll
            for (int j = 0; j < 4; ++j) s[j] = 0.f;
            for (int n = 0; n < HW; ++n) {
                float a = attnb[n][p];
                #pragma unroll
                for (int j = 0; j < 4; ++j)
                    s[j] = fmaf(qh[2 * CH + 4 * wv + j][n], a, s[j]);
            }
            #pragma unroll
            for (int j = 0; j < 4; ++j) outb[4 * wv + j][p] = s[j];
        }
        __syncthreads();   // (4)

        // --- Phase G: proj partial (no trailing barrier; see R2 analysis) ---
        if (act) {
            #pragma unroll 4
            for (int cc = 0; cc < CH; ++cc) {
                float ov = outb[cc][p];
                #pragma unroll
                for (int j = 0; j < 24; ++j)
                    pacc[j] = fmaf(w_proj[(24 * wv + j) * CIN + CH * h + cc], ov, pacc[j]);
            }
        }
    }

    // --- epilogue: bias + dense in-place store to this window's chunk ---
    // Safe: this block finished reading its chunk before the first barrier,
    // and chunks are block-private.
    float* __restrict__ ochunk = win + (size_t)wi * CHUNK;
    if (act) {
        #pragma unroll
        for (int j = 0; j < 24; ++j) {
            int oc = 24 * wv + j;
            ochunk[oc * HW + p] = pacc[j] + b_proj[oc];
        }
    }
}

// ---------- fallback (verified R2 kernel): direct scattered global I/O ----------
__global__ __launch_bounds__(512, 4)
void win_attn_direct(const float* __restrict__ x,
                     const float* __restrict__ w_qkv,
                     const float* __restrict__ b_qkv,
                     const float* __restrict__ w_dw,
                     const float* __restrict__ b_dw,
                     const float* __restrict__ w_proj,
                     const float* __restrict__ b_proj,
                     const float* __restrict__ temperature,
                     float* __restrict__ out)
{
    __shared__ float xs[CIN][HW];
    __shared__ float qh[96][HW];
    __shared__ float attnb[HW][ASTR];
    __shared__ float outb[CH][HW];

    const int tid  = threadIdx.x;
    const int lane = tid & 63;
    const int wv   = __builtin_amdgcn_readfirstlane(tid >> 6);

    const int wi   = blockIdx.x;
    const int b    = wi >> 10;
    const int hy   = (wi >> 5) & 31;
    const int wx   = wi & 31;
    const int row0 = hy * WSZ, col0 = wx * WSZ;

    const int  p   = lane;
    const bool act = (lane < HW);
    const int  py  = p / WSZ, px = p % WSZ;

    for (int i = tid; i < CIN * HW; i += 512) {
        int c = i / HW, pp = i - c * HW;
        int gy = row0 + pp / WSZ, gx = col0 + pp % WSZ;
        xs[c][pp] = x[((b * CIN + c) * IMG + gy) * IMG + gx];
    }
    __syncthreads();

    float pacc[24];
    #pragma unroll
    for (int j = 0; j < 24; ++j) pacc[j] = 0.f;

    for (int h = 0; h < HEADS; ++h) {
        int oj[12];
        #pragma unroll
        for (int j = 0; j < 12; ++j) {
            int r = 12 * wv + j;
            oj[j] = (r < 32) ? (CH * h + r)
                  : (r < 64) ? (CIN + CH * h + (r - 32))
                             : (2 * CIN + CH * h + (r - 64));
        }

        if (act) {
            float acc[12];
            #pragma unroll
            for (int j = 0; j < 12; ++j) acc[j] = 0.f;
            #pragma unroll 4
            for (int c = 0; c < CIN; ++c) {
                float xv = xs[c][p];
                #pragma unroll
                for (int j = 0; j < 12; ++j)
                    acc[j] = fmaf(w_qkv[oj[j] * CIN + c], xv, acc[j]);
            }
            #pragma unroll
            for (int j = 0; j < 12; ++j)
                qh[12 * wv + j][p] = acc[j] + b_qkv[oj[j]];
        }

        if (act) {
            float cv[12];
            #pragma unroll
            for (int j = 0; j < 12; ++j) {
                int r = 12 * wv + j, o = oj[j];
                float s = b_dw[o];
                #pragma unroll
                for (int ky = 0; ky < 3; ++ky) {
                    int yy = py + ky - 1;
                    #pragma unroll
                    for (int kx = 0; kx < 3; ++kx) {
                        int xx = px + kx - 1;
                        bool ok = (yy >= 0) & (yy < WSZ) & (xx >= 0) & (xx < WSZ);
                        float v = ok ? qh[r][yy * WSZ + xx] : 0.f;
                        s = fmaf(w_dw[o * 9 + ky * 3 + kx], v, s);
                    }
                }
                cv[j] = s;
            }
            #pragma unroll
            for (int j = 0; j < 12; ++j) qh[12 * wv + j][p] = cv[j];
        }
        __syncthreads();

        float rnq = 0.f, rnk = 0.f;
        if (act) {
            float sq = 0.f, sk = 0.f;
            #pragma unroll
            for (int cc = 0; cc < CH; ++cc) {
                float a  = qh[cc][p];      sq = fmaf(a, a, sq);
                float bb = qh[CH + cc][p]; sk = fmaf(bb, bb, sk);
            }
            rnq = 1.0f / fmaxf(sqrtf(sq), 1e-12f);
            rnk = 1.0f / fmaxf(sqrtf(sk), 1e-12f);
        }

        float qreg[CH];
        if (act) {
            #pragma unroll
            for (int cc = 0; cc < CH; ++cc) qreg[cc] = qh[cc][p];
        }

        const float tmp = temperature[h];
        {
            int n0 = (wv * HW) >> 3;
            int n1 = ((wv + 1) * HW) >> 3;
            for (int n = n0; n < n1; ++n) {
                float rkn = __shfl(rnk, n);
                if (act) {
                    float s = 0.f;
                    #pragma unroll
                    for (int cc = 0; cc < CH; ++cc)
                        s = fmaf(qh[CH + cc][n], qreg[cc], s);
                    attnb[n][p] = s * tmp * rkn * rnq;
                }
            }
        }
        __syncthreads();

        {
            int m = tid >> 3, sub = tid & 7;
            if (m < HW) {
                int na = (sub * HW) >> 3;
                int nb = ((sub + 1) * HW) >> 3;
                float mx = -1e30f;
                for (int n = na; n < nb; ++n) mx = fmaxf(mx, attnb[n][m]);
                mx = fmaxf(mx, __shfl_xor(mx, 1));
                mx = fmaxf(mx, __shfl_xor(mx, 2));
                mx = fmaxf(mx, __shfl_xor(mx, 4));
                float sum = 0.f;
                for (int n = na; n < nb; ++n) {
                    float e = __expf(attnb[n][m] - mx);
                    attnb[n][m] = e;
                    sum += e;
                }
                sum += __shfl_xor(sum, 1);
                sum += __shfl_xor(sum, 2);
                sum += __shfl_xor(sum, 4);
                float inv = 1.0f / sum;
                for (int n = na; n < nb; ++n) attnb[n][m] *= inv;
            }
        }
        __syncthreads();

        if (act) {
            float s[4];
            #pragma unroll
            for (int j = 0; j < 4; ++j) s[j] = 0.f;
            for (int n = 0; n < HW; ++n) {
                float a = attnb[n][p];
                #pragma unroll
                for (int j = 0; j < 4; ++j)
                    s[j] = fmaf(qh[2 * CH + 4 * wv + j][n], a, s[j]);
            }
            #pragma unroll
            for (int j = 0; j < 4; ++j) outb[4 * wv + j][p] = s[j];
        }
        __syncthreads();

        if (act) {
            #pragma unroll 4
            for (int cc = 0; cc < CH; ++cc) {
                float ov = outb[cc][p];
                #pragma unroll
                for (int j = 0; j < 24; ++j)
                    pacc[j] = fmaf(w_proj[(24 * wv + j) * CIN + CH * h + cc], ov, pacc[j]);
            }
        }
    }

    if (act) {
        #pragma unroll
        for (int j = 0; j < 24; ++j) {
            int oc = 24 * wv + j;
            out[((b * CIN + oc) * IMG + row0 + py) * IMG + col0 + px] = pacc[j] + b_proj[oc];
        }
    }
}
} // namespace

extern "C" void kernel_launch(void* const* d_in, const int* in_sizes, int n_in,
                              void* d_out, int out_size, void* d_ws, size_t ws_size,
                              hipStream_t stream) {
    const float* x      = (const float*)d_in[0];
    const float* w_qkv  = (const float*)d_in[1];
    const float* b_qkv  = (const float*)d_in[2];
    const float* w_dw   = (const float*)d_in[3];
    const float* b_dw   = (const float*)d_in[4];
    const float* w_proj = (const float*)d_in[5];
    const float* b_proj = (const float*)d_in[6];
    const float* temp   = (const float*)d_in[7];

    const size_t WS_NEEDED = (size_t)NWIN * CHUNK * sizeof(float);  // 154.1 MB

    if (d_ws != nullptr && ws_size >= WS_NEEDED) {
        float* ws = (float*)d_ws;
        win_pre<<<dim3(4 * 32 * 24), dim3(256), 0, stream>>>(x, ws);
        win_attn_fused<<<dim3(NWIN), dim3(512), 0, stream>>>(
            ws, w_qkv, b_qkv, w_dw, b_dw, w_proj, b_proj, temp);
        win_post<<<dim3(4 * 32 * 24), dim3(256), 0, stream>>>(ws, (float*)d_out);
    } else {
        // Workspace too small for chunked layout: verified direct-I/O kernel.
        win_attn_direct<<<dim3(NWIN), dim3(512), 0, stream>>>(
            x, w_qkv, b_qkv, w_dw, b_dw, w_proj, b_proj, temp, (float*)d_out);
    }
}